// Round 1
// baseline (662.062 us; speedup 1.0000x reference)
//
#include <hip/hip_runtime.h>

#define Bsz 4096
#define Fsz 32
#define Dsz 64
#define Psz 496
#define BT  128      // b-rows per block
#define VIP 65       // padded LDS row length for vi tile (65 -> conflict-free)

// Block: 256 threads. Thread tile: 4 b-rows x 8 e-cols.
//   tx = tid & 7   -> e-range [tx*8, tx*8+8)
//   ty = tid >> 3  -> b-range [ty*4, ty*4+4)   (ty in 0..31)
__global__ __launch_bounds__(256)
void bilinear_fp32_kernel(const float* __restrict__ in,
                          const float* __restrict__ W,
                          float* __restrict__ out) {
    __shared__ float sW[Dsz][Dsz];     // [d][e], 16 KB
    __shared__ float sVi[BT][VIP];     // [b_local][d], padded, ~33 KB

    const int p   = blockIdx.x;
    const int b0  = blockIdx.y * BT;
    const int tid = threadIdx.x;

    // Decode pair p -> (i, j), matching np.triu_indices(F, k=1) order.
    int i = 0, rem = p;
    while (rem >= Fsz - 1 - i) { rem -= Fsz - 1 - i; ++i; }
    const int j = i + 1 + rem;

    // ---- Stage W[p] (64x64 fp32) into LDS: 256 threads x 4 float4 ----
    {
        const float4* gW  = (const float4*)(W + (size_t)p * Dsz * Dsz);
        float4*       sWv = (float4*)(&sW[0][0]);
#pragma unroll
        for (int k = 0; k < 4; ++k) sWv[tid + k * 256] = gW[tid + k * 256];
    }

    // ---- Stage vi tile (128 rows x 64 d) into LDS ----
    // 16 threads per row, one float4 each; 16 rows per pass, 8 passes.
    {
        const int rowq = tid >> 4;   // 0..15
        const int q    = tid & 15;   // float4 index in row
#pragma unroll
        for (int pass = 0; pass < BT / 16; ++pass) {
            const int r = pass * 16 + rowq;
            const float4 v = *(const float4*)(in + ((size_t)(b0 + r) * Fsz + i) * Dsz + q * 4);
            sVi[r][q * 4 + 0] = v.x;
            sVi[r][q * 4 + 1] = v.y;
            sVi[r][q * 4 + 2] = v.z;
            sVi[r][q * 4 + 3] = v.w;
        }
    }

    __syncthreads();

    const int tx  = tid & 7;
    const int ty  = tid >> 3;
    const int e0  = tx * 8;
    const int bl0 = ty * 4;

    float acc[4][8];
#pragma unroll
    for (int bb = 0; bb < 4; ++bb)
#pragma unroll
        for (int ee = 0; ee < 8; ++ee) acc[bb][ee] = 0.0f;

    // ---- Inner product over d: 32 FMAs per d per thread ----
#pragma unroll 8
    for (int d = 0; d < Dsz; ++d) {
        float w[8];
        *(float4*)&w[0] = *(const float4*)&sW[d][e0];
        *(float4*)&w[4] = *(const float4*)&sW[d][e0 + 4];
        float v[4];
#pragma unroll
        for (int bb = 0; bb < 4; ++bb) v[bb] = sVi[bl0 + bb][d];
#pragma unroll
        for (int bb = 0; bb < 4; ++bb)
#pragma unroll
            for (int ee = 0; ee < 8; ++ee)
                acc[bb][ee] = fmaf(v[bb], w[ee], acc[bb][ee]);
    }

    // ---- Epilogue: multiply by vj and store ----
#pragma unroll
    for (int bb = 0; bb < 4; ++bb) {
        const size_t b   = (size_t)(b0 + bl0 + bb);
        const float* vjp = in + (b * Fsz + j) * Dsz + e0;
        const float4 vja = *(const float4*)(vjp);
        const float4 vjb = *(const float4*)(vjp + 4);
        float4 o0, o1;
        o0.x = acc[bb][0] * vja.x;
        o0.y = acc[bb][1] * vja.y;
        o0.z = acc[bb][2] * vja.z;
        o0.w = acc[bb][3] * vja.w;
        o1.x = acc[bb][4] * vjb.x;
        o1.y = acc[bb][5] * vjb.y;
        o1.z = acc[bb][6] * vjb.z;
        o1.w = acc[bb][7] * vjb.w;
        float* op = out + (b * Psz + p) * Dsz + e0;
        *(float4*)(op)     = o0;
        *(float4*)(op + 4) = o1;
    }
}

extern "C" void kernel_launch(void* const* d_in, const int* in_sizes, int n_in,
                              void* d_out, int out_size, void* d_ws, size_t ws_size,
                              hipStream_t stream) {
    const float* in  = (const float*)d_in[0];
    const float* W   = (const float*)d_in[1];
    float*       out = (float*)d_out;

    dim3 grid(Psz, Bsz / BT);
    bilinear_fp32_kernel<<<grid, 256, 0, stream>>>(in, W, out);
}